// Round 13
// baseline (242.585 us; speedup 1.0000x reference)
//
#include <hip/hip_runtime.h>
#include <hip/hip_bf16.h>

// B=8, N=1024, C=1024, H=16, HD=64
// R26: attn QBLK 256 -> 512 (1024-thread blocks, 16 waves x 32 q-rows,
//      grid (2,128) = 256 blocks = 1/CU). K/V re-reads per bh halve again
//      (4 -> 2 passes), barrier events per work halve, staging split
//      wave-uniformly (waves 0-7 stage K, 8-15 stage V, one float4/thread).
//      Occupancy unchanged (16 waves/CU). R24 softmax (cast-bf16 + setprio)
//      kept. QKV/proj/convert frozen at best-verified.

typedef __attribute__((ext_vector_type(8))) short bf16x8;
typedef __attribute__((ext_vector_type(4))) short bf16x4;
typedef __attribute__((ext_vector_type(4))) float f32x4;

__device__ __forceinline__ short f2bf(float f) {
    union { float f; unsigned u; } x;
    x.f = f;
    unsigned r = x.u + 0x7fffu + ((x.u >> 16) & 1u);  // RNE
    return (short)(r >> 16);
}

__device__ __forceinline__ short f2bf_cvt(float f) {
    __hip_bfloat16 h = __float2bfloat16(f);           // compiler RNE cast
    return *reinterpret_cast<short*>(&h);
}

__device__ __forceinline__ void load_lds16(const void* g, void* l) {
    __builtin_amdgcn_global_load_lds((const __attribute__((address_space(1))) unsigned*)g,
                                     (__attribute__((address_space(3))) unsigned*)l,
                                     16, 0, 0);
}

// ---------------- merged fp32 -> bf16 convert (frozen) ----------------
__global__ __launch_bounds__(256) void convert_all(const float* __restrict__ x,
                                                   const float* __restrict__ wqkv,
                                                   const float* __restrict__ wproj,
                                                   short* __restrict__ xb,
                                                   short* __restrict__ wqkvb,
                                                   short* __restrict__ wprojb) {
    int i = blockIdx.x * 256 + threadIdx.x;
    const float* src;
    short* dst;
    int j;
    if (i < 2097152)      { src = x;     dst = xb;     j = i; }
    else if (i < 2883584) { src = wqkv;  dst = wqkvb;  j = i - 2097152; }
    else                  { src = wproj; dst = wprojb; j = i - 2883584; }
    float4 v = *(const float4*)(src + j * 4);
    unsigned lo = (unsigned short)f2bf(v.x) | ((unsigned)(unsigned short)f2bf(v.y) << 16);
    unsigned hi = (unsigned short)f2bf(v.z) | ((unsigned)(unsigned short)f2bf(v.w) << 16);
    uint2 p; p.x = lo; p.y = hi;
    *(uint2*)(dst + j * 4) = p;
}

// ---------------- QKV GEMM: 512-thread 128x128 dbuf dist-1 (frozen) ----------------
__global__ __launch_bounds__(512, 4) void gemm_qkv5(const short* __restrict__ A,
                                                    const short* __restrict__ Bt,
                                                    short* __restrict__ q,
                                                    short* __restrict__ kk,
                                                    short* __restrict__ vt) {
    extern __shared__ short lds[];          // A[2][128][64] | B[2][128][64]
    const int K = 1024;
    constexpr int NTX = 24;
    constexpr int NWG = 64 * NTX;           // 1536
    constexpr int CHUNK = NWG / 8;

    const int bid = blockIdx.x;
    const int tile = (bid & 7) * CHUNK + (bid >> 3);   // XCD-bijective
    const int m0 = (tile / NTX) * 128;
    const int n0 = (tile % NTX) * 128;

    const int t = threadIdx.x;
    const int w = t >> 6, lane = t & 63, quad = lane >> 4, l16 = lane & 15;
    const int wm = (w >> 2) * 64, wn = (w & 3) * 32;
    const int sw = l16 & 7;

    const int srow = t >> 3;                            // 0..63
    const int scol = ((t & 7) ^ (srow & 7)) * 8;
    const short* Ag = A  + (m0 + srow) * K + scol;
    const short* Bg = Bt + (n0 + srow) * K + scol;
    const int w8 = w * 8 * 64;

    f32x4 acc[4][2];
    #pragma unroll
    for (int mi = 0; mi < 4; ++mi)
        #pragma unroll
        for (int ni = 0; ni < 2; ++ni) acc[mi][ni] = (f32x4){0.f, 0.f, 0.f, 0.f};

#define STG(kt_, d_) do { \
    _Pragma("unroll") \
    for (int r = 0; r < 2; ++r) \
        load_lds16(Ag + r * 64 * K + (kt_) * 64, lds + (d_) * 8192 + r * 64 * 64 + w8); \
    _Pragma("unroll") \
    for (int r = 0; r < 2; ++r) \
        load_lds16(Bg + r * 64 * K + (kt_) * 64, lds + 16384 + (d_) * 8192 + r * 64 * 64 + w8); } while (0)

    STG(0, 0);
    __syncthreads();

    #pragma unroll 1
    for (int kt = 0; kt < 16; ++kt) {
        const int d = kt & 1;
        if (kt < 15) STG(kt + 1, d ^ 1);

        const short* Ar = lds + d * 8192;
        const short* Br = lds + 16384 + d * 8192;
        bf16x8 af[4][2], bf[2][2];
        #pragma unroll
        for (int mi = 0; mi < 4; ++mi)
            #pragma unroll
            for (int c = 0; c < 2; ++c)
                af[mi][c] = *(const bf16x8*)(Ar + (wm + mi * 16 + l16) * 64 + (((quad + 4 * c) ^ sw) * 8));
        #pragma unroll
        for (int ni = 0; ni < 2; ++ni)
            #pragma unroll
            for (int c = 0; c < 2; ++c)
                bf[ni][c] = *(const bf16x8*)(Br + (wn + ni * 16 + l16) * 64 + (((quad + 4 * c) ^ sw) * 8));
        #pragma unroll
        for (int mi = 0; mi < 4; ++mi)
            #pragma unroll
            for (int ni = 0; ni < 2; ++ni) {
                acc[mi][ni] = __builtin_amdgcn_mfma_f32_16x16x32_bf16(af[mi][0], bf[ni][0], acc[mi][ni], 0, 0, 0);
                acc[mi][ni] = __builtin_amdgcn_mfma_f32_16x16x32_bf16(af[mi][1], bf[ni][1], acc[mi][ni], 0, 0, 0);
            }
        if (kt < 15) __syncthreads();
    }
#undef STG

    const float QS = 0.125f * 1.44269504088896f;
    #pragma unroll
    for (int ni = 0; ni < 2; ++ni) {
        int col = n0 + wn + ni * 16 + l16;
        int sect = col >> 10;
        int c = col & 1023;
        int h = c >> 6, dd = c & 63;
        #pragma unroll
        for (int mi = 0; mi < 4; ++mi) {
            #pragma unroll
            for (int r = 0; r < 4; ++r) {
                int m = m0 + wm + mi * 16 + quad * 4 + r;
                int b = m >> 10, i = m & 1023;
                float v = acc[mi][ni][r];
                if (sect == 0)      q[((b * 16 + h) * 1024 + i) * 64 + dd] = f2bf(v * QS);
                else if (sect == 1) kk[((b * 16 + h) * 1024 + i) * 64 + dd] = f2bf(v);
                else                vt[((b * 16 + h) * 64 + dd) * 1024 + i] = f2bf(v);
            }
        }
    }
}

// ---------------- proj GEMM: 512-thread dbuf dist-1 (frozen) ----------------
__global__ __launch_bounds__(512, 4) void gemm_proj5(const short* __restrict__ A,
                                                     const short* __restrict__ Bt,
                                                     const float* __restrict__ bias,
                                                     float* __restrict__ out) {
    extern __shared__ short lds[];          // A[2][128][64] | B[2][128][64]
    const int K = 1024;
    constexpr int NTX = 8;
    constexpr int NWG = 64 * NTX;           // 512
    constexpr int CHUNK = NWG / 8;

    const int bid = blockIdx.x;
    const int tile = (bid & 7) * CHUNK + (bid >> 3);
    const int m0 = (tile / NTX) * 128;
    const int n0 = (tile % NTX) * 128;

    const int t = threadIdx.x;
    const int w = t >> 6, lane = t & 63, quad = lane >> 4, l16 = lane & 15;
    const int wm = (w >> 2) * 64, wn = (w & 3) * 32;
    const int sw = l16 & 7;

    const int srow = t >> 3;
    const int scol = ((t & 7) ^ (srow & 7)) * 8;
    const short* Ag = A  + (m0 + srow) * K + scol;
    const short* Bg = Bt + (n0 + srow) * K + scol;
    const int w8 = w * 8 * 64;

    f32x4 acc[4][2];
    #pragma unroll
    for (int mi = 0; mi < 4; ++mi)
        #pragma unroll
        for (int ni = 0; ni < 2; ++ni) acc[mi][ni] = (f32x4){0.f, 0.f, 0.f, 0.f};

#define STG(kt_, d_) do { \
    _Pragma("unroll") \
    for (int r = 0; r < 2; ++r) \
        load_lds16(Ag + r * 64 * K + (kt_) * 64, lds + (d_) * 8192 + r * 64 * 64 + w8); \
    _Pragma("unroll") \
    for (int r = 0; r < 2; ++r) \
        load_lds16(Bg + r * 64 * K + (kt_) * 64, lds + 16384 + (d_) * 8192 + r * 64 * 64 + w8); } while (0)

    STG(0, 0);
    __syncthreads();

    #pragma unroll 1
    for (int kt = 0; kt < 16; ++kt) {
        const int d = kt & 1;
        if (kt < 15) STG(kt + 1, d ^ 1);

        const short* Ar = lds + d * 8192;
        const short* Br = lds + 16384 + d * 8192;
        bf16x8 af[4][2], bf[2][2];
        #pragma unroll
        for (int mi = 0; mi < 4; ++mi)
            #pragma unroll
            for (int c = 0; c < 2; ++c)
                af[mi][c] = *(const bf16x8*)(Ar + (wm + mi * 16 + l16) * 64 + (((quad + 4 * c) ^ sw) * 8));
        #pragma unroll
        for (int ni = 0; ni < 2; ++ni)
            #pragma unroll
            for (int c = 0; c < 2; ++c)
                bf[ni][c] = *(const bf16x8*)(Br + (wn + ni * 16 + l16) * 64 + (((quad + 4 * c) ^ sw) * 8));
        #pragma unroll
        for (int mi = 0; mi < 4; ++mi)
            #pragma unroll
            for (int ni = 0; ni < 2; ++ni) {
                acc[mi][ni] = __builtin_amdgcn_mfma_f32_16x16x32_bf16(af[mi][0], bf[ni][0], acc[mi][ni], 0, 0, 0);
                acc[mi][ni] = __builtin_amdgcn_mfma_f32_16x16x32_bf16(af[mi][1], bf[ni][1], acc[mi][ni], 0, 0, 0);
            }
        if (kt < 15) __syncthreads();
    }
#undef STG

    #pragma unroll
    for (int ni = 0; ni < 2; ++ni) {
        int col = n0 + wn + ni * 16 + l16;
        float bv = bias[col];
        #pragma unroll
        for (int mi = 0; mi < 4; ++mi) {
            #pragma unroll
            for (int r = 0; r < 4; ++r) {
                int m = m0 + wm + mi * 16 + quad * 4 + r;
                out[m * 1024 + col] = acc[mi][ni][r] + bv;
            }
        }
    }
}

// ---------------- Flash attention: 1024-thr QBLK=512, split K/V staging ----------------
__global__ __launch_bounds__(1024) void attn_kernel(const short* __restrict__ q,
                                                    const short* __restrict__ k,
                                                    const short* __restrict__ vt,
                                                    short* __restrict__ ao) {
    __shared__ alignas(16) short Ks[2][64][72];
    __shared__ alignas(16) short Vs[2][64][72];

    const int bh = blockIdx.y, qt = blockIdx.x;
    const int t = threadIdx.x, w = t >> 6, lane = t & 63, quad = lane >> 4, l16 = lane & 15;
    const short* qg = q  + (bh * 1024 + qt * 512) * 64;
    const short* kg = k  + bh * 65536;
    const short* vg = vt + bh * 65536;

    bf16x8 qf[2][2];
    for (int mi = 0; mi < 2; ++mi) {
        const short* qr = qg + (w * 32 + mi * 16 + l16) * 64;
        qf[mi][0] = *(const bf16x8*)(qr + quad * 8);
        qf[mi][1] = *(const bf16x8*)(qr + 32 + quad * 8);
    }

    // staging split: waves 0-7 stage K, waves 8-15 stage V; one float4/thread
    const int half = t >> 9;                 // 0: K, 1: V (wave-uniform)
    const int r0 = (t & 511) >> 3;           // 0..63
    const int c80 = (t & 7) * 8;

    float rs[2] = {0.f, 0.f};
    f32x4 oaccT[2][4];
    for (int mi = 0; mi < 2; ++mi)
        for (int dt = 0; dt < 4; ++dt) oaccT[mi][dt] = (f32x4){0.f, 0.f, 0.f, 0.f};

    if (half == 0) *(float4*)&Ks[0][r0][c80] = *(const float4*)&kg[r0 * 64 + c80];
    else           *(float4*)&Vs[0][r0][c80] = *(const float4*)&vg[r0 * 1024 + c80];

    for (int jt = 0; jt < 16; ++jt) {
        const int cur = jt & 1;
        asm volatile("s_waitcnt lgkmcnt(0)" ::: "memory");
        asm volatile("s_barrier" ::: "memory");

        float4 pre;
        if (jt < 15) {
            int jn = jt + 1;
            pre = (half == 0) ? *(const float4*)&kg[(jn * 64 + r0) * 64 + c80]
                              : *(const float4*)&vg[r0 * 1024 + jn * 64 + c80];
        }

        for (int js = 0; js < 4; ++js) {
            bf16x8 kf0 = *(const bf16x8*)&Ks[cur][js * 16 + l16][quad * 8];
            bf16x8 kf1 = *(const bf16x8*)&Ks[cur][js * 16 + l16][32 + quad * 8];
            bf16x4 vtf[4];
            for (int dt = 0; dt < 4; ++dt)
                vtf[dt] = *(const bf16x4*)&Vs[cur][dt * 16 + l16][js * 16 + quad * 4];
            for (int mi = 0; mi < 2; ++mi) {
                f32x4 s = (f32x4){0.f, 0.f, 0.f, 0.f};
                __builtin_amdgcn_s_setprio(1);
                s = __builtin_amdgcn_mfma_f32_16x16x32_bf16(kf0, qf[mi][0], s, 0, 0, 0);
                s = __builtin_amdgcn_mfma_f32_16x16x32_bf16(kf1, qf[mi][1], s, 0, 0, 0);
                __builtin_amdgcn_s_setprio(0);
                bf16x4 pfrag;
                #pragma unroll
                for (int r = 0; r < 4; ++r) {
                    float p = __builtin_amdgcn_exp2f(s[r]);
                    rs[mi] += p;
                    pfrag[r] = f2bf_cvt(p);
                }
                __builtin_amdgcn_s_setprio(1);
                #pragma unroll
                for (int dt = 0; dt < 4; ++dt)
                    oaccT[mi][dt] = __builtin_amdgcn_mfma_f32_16x16x16bf16_1k(
                        vtf[dt], pfrag, oaccT[mi][dt], 0, 0, 0);
                __builtin_amdgcn_s_setprio(0);
            }
        }

        if (jt < 15) {
            const int nxt = cur ^ 1;
            if (half == 0) *(float4*)&Ks[nxt][r0][c80] = pre;
            else           *(float4*)&Vs[nxt][r0][c80] = pre;
        }
    }

    for (int mi = 0; mi < 2; ++mi) {
        rs[mi] += __shfl_xor(rs[mi], 16, 64);
        rs[mi] += __shfl_xor(rs[mi], 32, 64);
    }

    const int b = bh >> 4, h = bh & 15;
    for (int mi = 0; mi < 2; ++mi) {
        float inv = 1.0f / rs[mi];
        int i = qt * 512 + w * 32 + mi * 16 + l16;
        short* aor = ao + (b * 1024 + i) * 1024 + h * 64;
        for (int dt = 0; dt < 4; ++dt) {
            bf16x4 o4;
            #pragma unroll
            for (int r = 0; r < 4; ++r) o4[r] = f2bf_cvt(oaccT[mi][dt][r] * inv);
            *(bf16x4*)(aor + dt * 16 + quad * 4) = o4;
        }
    }
}

extern "C" void kernel_launch(void* const* d_in, const int* in_sizes, int n_in,
                              void* d_out, int out_size, void* d_ws, size_t ws_size,
                              hipStream_t stream) {
    const float* x      = (const float*)d_in[0];
    const float* w_qkv  = (const float*)d_in[1];
    const float* w_proj = (const float*)d_in[2];
    const float* b_proj = (const float*)d_in[3];
    float* out = (float*)d_out;

    char* ws = (char*)d_ws;
    short* xb     = (short*)(ws);
    short* wqkvb  = (short*)(ws + 16777216);
    short* wprojb = (short*)(ws + 23068672);
    short* qb     = (short*)(ws + 25165824);
    short* kb     = (short*)(ws + 41943040);
    short* vtb    = (short*)(ws + 58720256);
    short* aob    = (short*)(ws + 75497472);

    static bool s_init = false;
    if (!s_init) {
        hipFuncSetAttribute(reinterpret_cast<const void*>(&gemm_qkv5),
                            hipFuncAttributeMaxDynamicSharedMemorySize, 65536);
        hipFuncSetAttribute(reinterpret_cast<const void*>(&gemm_proj5),
                            hipFuncAttributeMaxDynamicSharedMemorySize, 65536);
        s_init = true;
    }

    convert_all<<<12288, 256, 0, stream>>>(x, w_qkv, w_proj, xb, wqkvb, wprojb);
    gemm_qkv5<<<1536, 512, 65536, stream>>>(xb, wqkvb, qb, kb, vtb);
    // attn: QBLK=512 -> grid (2, 128), 1024 threads, 1 block/CU
    attn_kernel<<<dim3(2, 128), 1024, 0, stream>>>(qb, kb, vtb, aob);
    gemm_proj5<<<512, 512, 65536, stream>>>(aob, wprojb, b_proj, out);
}

// Round 14
// 237.064 us; speedup vs baseline: 1.0233x; 1.0233x over previous
//
#include <hip/hip_runtime.h>
#include <hip/hip_bf16.h>

// B=8, N=1024, C=1024, H=16, HD=64
// R27: revert attn to R25 (best measured, 237.3us total): QBLK=256,
//      512-thread blocks (8 waves x 32 q-rows), grid (4,128), dbuf K/V,
//      cast-bf16 softmax + setprio. R26's QBLK=512 regressed (-5us): 16
//      waves contending one K/V buffer pair + wider barrier tail beat the
//      (L2-resident) staging saving. QKV/proj/convert frozen (unchanged
//      since R23/R24 best-verified).

typedef __attribute__((ext_vector_type(8))) short bf16x8;
typedef __attribute__((ext_vector_type(4))) short bf16x4;
typedef __attribute__((ext_vector_type(4))) float f32x4;

__device__ __forceinline__ short f2bf(float f) {
    union { float f; unsigned u; } x;
    x.f = f;
    unsigned r = x.u + 0x7fffu + ((x.u >> 16) & 1u);  // RNE
    return (short)(r >> 16);
}

__device__ __forceinline__ short f2bf_cvt(float f) {
    __hip_bfloat16 h = __float2bfloat16(f);           // compiler RNE cast
    return *reinterpret_cast<short*>(&h);
}

__device__ __forceinline__ void load_lds16(const void* g, void* l) {
    __builtin_amdgcn_global_load_lds((const __attribute__((address_space(1))) unsigned*)g,
                                     (__attribute__((address_space(3))) unsigned*)l,
                                     16, 0, 0);
}

// ---------------- merged fp32 -> bf16 convert (frozen) ----------------
__global__ __launch_bounds__(256) void convert_all(const float* __restrict__ x,
                                                   const float* __restrict__ wqkv,
                                                   const float* __restrict__ wproj,
                                                   short* __restrict__ xb,
                                                   short* __restrict__ wqkvb,
                                                   short* __restrict__ wprojb) {
    int i = blockIdx.x * 256 + threadIdx.x;
    const float* src;
    short* dst;
    int j;
    if (i < 2097152)      { src = x;     dst = xb;     j = i; }
    else if (i < 2883584) { src = wqkv;  dst = wqkvb;  j = i - 2097152; }
    else                  { src = wproj; dst = wprojb; j = i - 2883584; }
    float4 v = *(const float4*)(src + j * 4);
    unsigned lo = (unsigned short)f2bf(v.x) | ((unsigned)(unsigned short)f2bf(v.y) << 16);
    unsigned hi = (unsigned short)f2bf(v.z) | ((unsigned)(unsigned short)f2bf(v.w) << 16);
    uint2 p; p.x = lo; p.y = hi;
    *(uint2*)(dst + j * 4) = p;
}

// ---------------- QKV GEMM: 512-thread 128x128 dbuf dist-1 (frozen) ----------------
__global__ __launch_bounds__(512, 4) void gemm_qkv5(const short* __restrict__ A,
                                                    const short* __restrict__ Bt,
                                                    short* __restrict__ q,
                                                    short* __restrict__ kk,
                                                    short* __restrict__ vt) {
    extern __shared__ short lds[];          // A[2][128][64] | B[2][128][64]
    const int K = 1024;
    constexpr int NTX = 24;
    constexpr int NWG = 64 * NTX;           // 1536
    constexpr int CHUNK = NWG / 8;

    const int bid = blockIdx.x;
    const int tile = (bid & 7) * CHUNK + (bid >> 3);   // XCD-bijective
    const int m0 = (tile / NTX) * 128;
    const int n0 = (tile % NTX) * 128;

    const int t = threadIdx.x;
    const int w = t >> 6, lane = t & 63, quad = lane >> 4, l16 = lane & 15;
    const int wm = (w >> 2) * 64, wn = (w & 3) * 32;
    const int sw = l16 & 7;

    const int srow = t >> 3;                            // 0..63
    const int scol = ((t & 7) ^ (srow & 7)) * 8;
    const short* Ag = A  + (m0 + srow) * K + scol;
    const short* Bg = Bt + (n0 + srow) * K + scol;
    const int w8 = w * 8 * 64;

    f32x4 acc[4][2];
    #pragma unroll
    for (int mi = 0; mi < 4; ++mi)
        #pragma unroll
        for (int ni = 0; ni < 2; ++ni) acc[mi][ni] = (f32x4){0.f, 0.f, 0.f, 0.f};

#define STG(kt_, d_) do { \
    _Pragma("unroll") \
    for (int r = 0; r < 2; ++r) \
        load_lds16(Ag + r * 64 * K + (kt_) * 64, lds + (d_) * 8192 + r * 64 * 64 + w8); \
    _Pragma("unroll") \
    for (int r = 0; r < 2; ++r) \
        load_lds16(Bg + r * 64 * K + (kt_) * 64, lds + 16384 + (d_) * 8192 + r * 64 * 64 + w8); } while (0)

    STG(0, 0);
    __syncthreads();

    #pragma unroll 1
    for (int kt = 0; kt < 16; ++kt) {
        const int d = kt & 1;
        if (kt < 15) STG(kt + 1, d ^ 1);

        const short* Ar = lds + d * 8192;
        const short* Br = lds + 16384 + d * 8192;
        bf16x8 af[4][2], bf[2][2];
        #pragma unroll
        for (int mi = 0; mi < 4; ++mi)
            #pragma unroll
            for (int c = 0; c < 2; ++c)
                af[mi][c] = *(const bf16x8*)(Ar + (wm + mi * 16 + l16) * 64 + (((quad + 4 * c) ^ sw) * 8));
        #pragma unroll
        for (int ni = 0; ni < 2; ++ni)
            #pragma unroll
            for (int c = 0; c < 2; ++c)
                bf[ni][c] = *(const bf16x8*)(Br + (wn + ni * 16 + l16) * 64 + (((quad + 4 * c) ^ sw) * 8));
        #pragma unroll
        for (int mi = 0; mi < 4; ++mi)
            #pragma unroll
            for (int ni = 0; ni < 2; ++ni) {
                acc[mi][ni] = __builtin_amdgcn_mfma_f32_16x16x32_bf16(af[mi][0], bf[ni][0], acc[mi][ni], 0, 0, 0);
                acc[mi][ni] = __builtin_amdgcn_mfma_f32_16x16x32_bf16(af[mi][1], bf[ni][1], acc[mi][ni], 0, 0, 0);
            }
        if (kt < 15) __syncthreads();
    }
#undef STG

    const float QS = 0.125f * 1.44269504088896f;
    #pragma unroll
    for (int ni = 0; ni < 2; ++ni) {
        int col = n0 + wn + ni * 16 + l16;
        int sect = col >> 10;
        int c = col & 1023;
        int h = c >> 6, dd = c & 63;
        #pragma unroll
        for (int mi = 0; mi < 4; ++mi) {
            #pragma unroll
            for (int r = 0; r < 4; ++r) {
                int m = m0 + wm + mi * 16 + quad * 4 + r;
                int b = m >> 10, i = m & 1023;
                float v = acc[mi][ni][r];
                if (sect == 0)      q[((b * 16 + h) * 1024 + i) * 64 + dd] = f2bf(v * QS);
                else if (sect == 1) kk[((b * 16 + h) * 1024 + i) * 64 + dd] = f2bf(v);
                else                vt[((b * 16 + h) * 64 + dd) * 1024 + i] = f2bf(v);
            }
        }
    }
}

// ---------------- proj GEMM: 512-thread dbuf dist-1 (frozen) ----------------
__global__ __launch_bounds__(512, 4) void gemm_proj5(const short* __restrict__ A,
                                                     const short* __restrict__ Bt,
                                                     const float* __restrict__ bias,
                                                     float* __restrict__ out) {
    extern __shared__ short lds[];          // A[2][128][64] | B[2][128][64]
    const int K = 1024;
    constexpr int NTX = 8;
    constexpr int NWG = 64 * NTX;           // 512
    constexpr int CHUNK = NWG / 8;

    const int bid = blockIdx.x;
    const int tile = (bid & 7) * CHUNK + (bid >> 3);
    const int m0 = (tile / NTX) * 128;
    const int n0 = (tile % NTX) * 128;

    const int t = threadIdx.x;
    const int w = t >> 6, lane = t & 63, quad = lane >> 4, l16 = lane & 15;
    const int wm = (w >> 2) * 64, wn = (w & 3) * 32;
    const int sw = l16 & 7;

    const int srow = t >> 3;
    const int scol = ((t & 7) ^ (srow & 7)) * 8;
    const short* Ag = A  + (m0 + srow) * K + scol;
    const short* Bg = Bt + (n0 + srow) * K + scol;
    const int w8 = w * 8 * 64;

    f32x4 acc[4][2];
    #pragma unroll
    for (int mi = 0; mi < 4; ++mi)
        #pragma unroll
        for (int ni = 0; ni < 2; ++ni) acc[mi][ni] = (f32x4){0.f, 0.f, 0.f, 0.f};

#define STG(kt_, d_) do { \
    _Pragma("unroll") \
    for (int r = 0; r < 2; ++r) \
        load_lds16(Ag + r * 64 * K + (kt_) * 64, lds + (d_) * 8192 + r * 64 * 64 + w8); \
    _Pragma("unroll") \
    for (int r = 0; r < 2; ++r) \
        load_lds16(Bg + r * 64 * K + (kt_) * 64, lds + 16384 + (d_) * 8192 + r * 64 * 64 + w8); } while (0)

    STG(0, 0);
    __syncthreads();

    #pragma unroll 1
    for (int kt = 0; kt < 16; ++kt) {
        const int d = kt & 1;
        if (kt < 15) STG(kt + 1, d ^ 1);

        const short* Ar = lds + d * 8192;
        const short* Br = lds + 16384 + d * 8192;
        bf16x8 af[4][2], bf[2][2];
        #pragma unroll
        for (int mi = 0; mi < 4; ++mi)
            #pragma unroll
            for (int c = 0; c < 2; ++c)
                af[mi][c] = *(const bf16x8*)(Ar + (wm + mi * 16 + l16) * 64 + (((quad + 4 * c) ^ sw) * 8));
        #pragma unroll
        for (int ni = 0; ni < 2; ++ni)
            #pragma unroll
            for (int c = 0; c < 2; ++c)
                bf[ni][c] = *(const bf16x8*)(Br + (wn + ni * 16 + l16) * 64 + (((quad + 4 * c) ^ sw) * 8));
        #pragma unroll
        for (int mi = 0; mi < 4; ++mi)
            #pragma unroll
            for (int ni = 0; ni < 2; ++ni) {
                acc[mi][ni] = __builtin_amdgcn_mfma_f32_16x16x32_bf16(af[mi][0], bf[ni][0], acc[mi][ni], 0, 0, 0);
                acc[mi][ni] = __builtin_amdgcn_mfma_f32_16x16x32_bf16(af[mi][1], bf[ni][1], acc[mi][ni], 0, 0, 0);
            }
        if (kt < 15) __syncthreads();
    }
#undef STG

    #pragma unroll
    for (int ni = 0; ni < 2; ++ni) {
        int col = n0 + wn + ni * 16 + l16;
        float bv = bias[col];
        #pragma unroll
        for (int mi = 0; mi < 4; ++mi) {
            #pragma unroll
            for (int r = 0; r < 4; ++r) {
                int m = m0 + wm + mi * 16 + quad * 4 + r;
                out[m * 1024 + col] = acc[mi][ni][r] + bv;
            }
        }
    }
}

// ---------------- Flash attention: 512-thr QBLK=256 (R25 best), dbuf K/V ----------------
__global__ __launch_bounds__(512) void attn_kernel(const short* __restrict__ q,
                                                   const short* __restrict__ k,
                                                   const short* __restrict__ vt,
                                                   short* __restrict__ ao) {
    __shared__ alignas(16) short Ks[2][64][72];
    __shared__ alignas(16) short Vs[2][64][72];

    const int bh = blockIdx.y, qt = blockIdx.x;
    const int t = threadIdx.x, w = t >> 6, lane = t & 63, quad = lane >> 4, l16 = lane & 15;
    const short* qg = q  + (bh * 1024 + qt * 256) * 64;
    const short* kg = k  + bh * 65536;
    const short* vg = vt + bh * 65536;

    bf16x8 qf[2][2];
    for (int mi = 0; mi < 2; ++mi) {
        const short* qr = qg + (w * 32 + mi * 16 + l16) * 64;
        qf[mi][0] = *(const bf16x8*)(qr + quad * 8);
        qf[mi][1] = *(const bf16x8*)(qr + 32 + quad * 8);
    }

    const int r0 = t >> 3, c80 = (t & 7) * 8;          // 512 thr cover 64x64 in one shot

    float rs[2] = {0.f, 0.f};
    f32x4 oaccT[2][4];
    for (int mi = 0; mi < 2; ++mi)
        for (int dt = 0; dt < 4; ++dt) oaccT[mi][dt] = (f32x4){0.f, 0.f, 0.f, 0.f};

    {
        float4 a = *(const float4*)&kg[r0 * 64 + c80];
        float4 c = *(const float4*)&vg[r0 * 1024 + c80];
        *(float4*)&Ks[0][r0][c80] = a;
        *(float4*)&Vs[0][r0][c80] = c;
    }

    for (int jt = 0; jt < 16; ++jt) {
        const int cur = jt & 1;
        asm volatile("s_waitcnt lgkmcnt(0)" ::: "memory");
        asm volatile("s_barrier" ::: "memory");

        float4 kr0, vr0;
        if (jt < 15) {
            int jn = jt + 1;
            kr0 = *(const float4*)&kg[(jn * 64 + r0) * 64 + c80];
            vr0 = *(const float4*)&vg[r0 * 1024 + jn * 64 + c80];
        }

        for (int js = 0; js < 4; ++js) {
            bf16x8 kf0 = *(const bf16x8*)&Ks[cur][js * 16 + l16][quad * 8];
            bf16x8 kf1 = *(const bf16x8*)&Ks[cur][js * 16 + l16][32 + quad * 8];
            bf16x4 vtf[4];
            for (int dt = 0; dt < 4; ++dt)
                vtf[dt] = *(const bf16x4*)&Vs[cur][dt * 16 + l16][js * 16 + quad * 4];
            for (int mi = 0; mi < 2; ++mi) {
                f32x4 s = (f32x4){0.f, 0.f, 0.f, 0.f};
                __builtin_amdgcn_s_setprio(1);
                s = __builtin_amdgcn_mfma_f32_16x16x32_bf16(kf0, qf[mi][0], s, 0, 0, 0);
                s = __builtin_amdgcn_mfma_f32_16x16x32_bf16(kf1, qf[mi][1], s, 0, 0, 0);
                __builtin_amdgcn_s_setprio(0);
                bf16x4 pfrag;
                #pragma unroll
                for (int r = 0; r < 4; ++r) {
                    float p = __builtin_amdgcn_exp2f(s[r]);
                    rs[mi] += p;
                    pfrag[r] = f2bf_cvt(p);
                }
                __builtin_amdgcn_s_setprio(1);
                #pragma unroll
                for (int dt = 0; dt < 4; ++dt)
                    oaccT[mi][dt] = __builtin_amdgcn_mfma_f32_16x16x16bf16_1k(
                        vtf[dt], pfrag, oaccT[mi][dt], 0, 0, 0);
                __builtin_amdgcn_s_setprio(0);
            }
        }

        if (jt < 15) {
            const int nxt = cur ^ 1;
            *(float4*)&Ks[nxt][r0][c80] = kr0;
            *(float4*)&Vs[nxt][r0][c80] = vr0;
        }
    }

    for (int mi = 0; mi < 2; ++mi) {
        rs[mi] += __shfl_xor(rs[mi], 16, 64);
        rs[mi] += __shfl_xor(rs[mi], 32, 64);
    }

    const int b = bh >> 4, h = bh & 15;
    for (int mi = 0; mi < 2; ++mi) {
        float inv = 1.0f / rs[mi];
        int i = qt * 256 + w * 32 + mi * 16 + l16;
        short* aor = ao + (b * 1024 + i) * 1024 + h * 64;
        for (int dt = 0; dt < 4; ++dt) {
            bf16x4 o4;
            #pragma unroll
            for (int r = 0; r < 4; ++r) o4[r] = f2bf_cvt(oaccT[mi][dt][r] * inv);
            *(bf16x4*)(aor + dt * 16 + quad * 4) = o4;
        }
    }
}

extern "C" void kernel_launch(void* const* d_in, const int* in_sizes, int n_in,
                              void* d_out, int out_size, void* d_ws, size_t ws_size,
                              hipStream_t stream) {
    const float* x      = (const float*)d_in[0];
    const float* w_qkv  = (const float*)d_in[1];
    const float* w_proj = (const float*)d_in[2];
    const float* b_proj = (const float*)d_in[3];
    float* out = (float*)d_out;

    char* ws = (char*)d_ws;
    short* xb     = (short*)(ws);
    short* wqkvb  = (short*)(ws + 16777216);
    short* wprojb = (short*)(ws + 23068672);
    short* qb     = (short*)(ws + 25165824);
    short* kb     = (short*)(ws + 41943040);
    short* vtb    = (short*)(ws + 58720256);
    short* aob    = (short*)(ws + 75497472);

    static bool s_init = false;
    if (!s_init) {
        hipFuncSetAttribute(reinterpret_cast<const void*>(&gemm_qkv5),
                            hipFuncAttributeMaxDynamicSharedMemorySize, 65536);
        hipFuncSetAttribute(reinterpret_cast<const void*>(&gemm_proj5),
                            hipFuncAttributeMaxDynamicSharedMemorySize, 65536);
        s_init = true;
    }

    convert_all<<<12288, 256, 0, stream>>>(x, w_qkv, w_proj, xb, wqkvb, wprojb);
    gemm_qkv5<<<1536, 512, 65536, stream>>>(xb, wqkvb, qb, kb, vtb);
    // attn: QBLK=256 -> grid (4, 128), 512 threads (R25 best)
    attn_kernel<<<dim3(4, 128), 512, 0, stream>>>(qb, kb, vtb, aob);
    gemm_proj5<<<512, 512, 65536, stream>>>(aob, wprojb, b_proj, out);
}